// Round 7
// baseline (291.829 us; speedup 1.0000x reference)
//
#include <hip/hip_runtime.h>

typedef short v8s __attribute__((ext_vector_type(8)));
typedef _Float16 v8h __attribute__((ext_vector_type(8)));
typedef float v4f __attribute__((ext_vector_type(4)));
typedef unsigned short u16;

// All on-chip/intermediate tensors are fp16: values bounded (L2-normed Q/K,
// |S|<=1/temp, A<=1, conv outputs O(1)), so fp16 beats bf16 accuracy AND
// f32->f16 is 1 VALU op. MFMA f16 rate == bf16 rate on gfx950.
#define MFMA_F16(a, b, c) __builtin_amdgcn_mfma_f32_16x16x32_f16((a), (b), (c), 0, 0, 0)
#define XS 72   // row stride in 16-bit elems (144 B, 16B-aligned rows)

__device__ __forceinline__ u16 f16r(float x) {
    _Float16 h = (_Float16)x; u16 u; __builtin_memcpy(&u, &h, 2); return u;
}
__device__ __forceinline__ float f16f(u16 u) {
    _Float16 h; __builtin_memcpy(&h, &u, 2); return (float)h;
}

// ---------------------------------------------------------------------------
// Stage-1 1x1 conv pieces. mm_frags/mm_store split lets k2 run the V path
// in-place (read B0 -> barrier -> write B0), enabling k2's 3-buffer layout
// (27648 B -> 5 blocks/CU; measured -23us on k2 in round 5).
// ---------------------------------------------------------------------------
__device__ __forceinline__ void mm_frags(const u16* __restrict__ Ag,
                                         const u16* __restrict__ XB,
                                         int wv, int L, int q, v4f C[4])
{
#pragma unroll
    for (int nt = 0; nt < 4; ++nt) C[nt] = (v4f){0.f, 0.f, 0.f, 0.f};
#pragma unroll
    for (int kt = 0; kt < 2; ++kt) {
        v8h a = *(const v8h*)(Ag + (16 * wv + L) * 64 + kt * 32 + q * 8);
#pragma unroll
        for (int nt = 0; nt < 4; ++nt) {
            v8h b = *(const v8h*)(XB + (nt * 16 + L) * XS + kt * 32 + q * 8);
            C[nt] = MFMA_F16(a, b, C[nt]);
        }
    }
}
__device__ __forceinline__ void mm_store(const v4f C[4], u16* __restrict__ M,
                                         int wv, int L, int q)
{
    const int rowb = 16 * wv + 4 * q;
#pragma unroll
    for (int r = 0; r < 4; ++r)
#pragma unroll
        for (int nt = 0; nt < 4; ++nt)
            M[(rowb + r) * XS + nt * 16 + L] = f16r(C[nt][r]);
}
__device__ __forceinline__ void mm_stage(const u16* __restrict__ Ag,
                                         const u16* __restrict__ XB,
                                         u16* __restrict__ M,
                                         int wv, int L, int q)
{
    v4f C[4];
    mm_frags(Ag, XB, wv, L, q, C);
    mm_store(C, M, wv, L, q);
}

// dw 3x3 input read: channel c, spatial rows r0-1..r0+2 from fp16 [c][p].
__device__ __forceinline__ void dw_read(const u16* __restrict__ M, int c, int r0,
                                        v8s raw[4])
{
#pragma unroll
    for (int r = 0; r < 4; ++r) {
        const int rr = r0 - 1 + r;
        raw[r] = ((unsigned)rr < 8u) ? *(const v8s*)(M + c * XS + rr * 8)
                                     : (v8s){0, 0, 0, 0, 0, 0, 0, 0};
    }
}

// dw 3x3 compute + optional L2-norm + f16 write.
// TR=false: [c][p] row-major (v8s packed). TR=true: transposed [p][c] scalar.
template <bool TR, bool NORM>
__device__ __forceinline__ void dw_write(const float* __restrict__ dwg,
                                         const v8s raw[4], int c, int r0,
                                         u16* __restrict__ Out)
{
    float w[9];
#pragma unroll
    for (int k = 0; k < 9; ++k) w[k] = dwg[c * 9 + k];
    float in[4][10];
#pragma unroll
    for (int r = 0; r < 4; ++r) {
        in[r][0] = 0.f; in[r][9] = 0.f;
#pragma unroll
        for (int j = 0; j < 8; ++j) in[r][j + 1] = f16f((u16)raw[r][j]);
    }
    float o[2][8];
#pragma unroll
    for (int rr = 0; rr < 2; ++rr)
#pragma unroll
        for (int j = 0; j < 8; ++j) {
            float s;
            s = w[0] * in[rr][j];
            s = fmaf(w[1], in[rr][j + 1], s);
            s = fmaf(w[2], in[rr][j + 2], s);
            s = fmaf(w[3], in[rr + 1][j], s);
            s = fmaf(w[4], in[rr + 1][j + 1], s);
            s = fmaf(w[5], in[rr + 1][j + 2], s);
            s = fmaf(w[6], in[rr + 2][j], s);
            s = fmaf(w[7], in[rr + 2][j + 1], s);
            s = fmaf(w[8], in[rr + 2][j + 2], s);
            o[rr][j] = s;
        }
    if (NORM) {
        float ss = 0.f;
#pragma unroll
        for (int rr = 0; rr < 2; ++rr)
#pragma unroll
            for (int j = 0; j < 8; ++j) ss = fmaf(o[rr][j], o[rr][j], ss);
        ss += __shfl_xor(ss, 1);
        ss += __shfl_xor(ss, 2);
        const float sc = 1.0f / fmaxf(sqrtf(ss), 1e-12f);
#pragma unroll
        for (int rr = 0; rr < 2; ++rr)
#pragma unroll
            for (int j = 0; j < 8; ++j) o[rr][j] *= sc;
    }
    if (TR) {
#pragma unroll
        for (int rr = 0; rr < 2; ++rr)
#pragma unroll
            for (int j = 0; j < 8; ++j)
                Out[((r0 + rr) * 8 + j) * XS + c] = f16r(o[rr][j]);
    } else {
#pragma unroll
        for (int rr = 0; rr < 2; ++rr) {
            v8s v;
#pragma unroll
            for (int j = 0; j < 8; ++j) v[j] = (short)f16r(o[rr][j]);
            *(v8s*)(Out + c * XS + (r0 + rr) * 8) = v;
        }
    }
}

// 64x64x64 D[m][n] = sum_k A[m][k]*B[n][k], both f16 LDS, wave stripe rows.
__device__ __forceinline__ void mm_lds(const u16* __restrict__ Am,
                                       const u16* __restrict__ Bm,
                                       int wv, int L, int q, v4f C[4])
{
#pragma unroll
    for (int nt = 0; nt < 4; ++nt) C[nt] = (v4f){0.f, 0.f, 0.f, 0.f};
#pragma unroll
    for (int kt = 0; kt < 2; ++kt) {
        v8h a = *(const v8h*)(Am + (16 * wv + L) * XS + kt * 32 + q * 8);
#pragma unroll
        for (int nt = 0; nt < 4; ++nt) {
            v8h b = *(const v8h*)(Bm + (nt * 16 + L) * XS + kt * 32 + q * 8);
            C[nt] = MFMA_F16(a, b, C[nt]);
        }
    }
}

// proj 3x3 dense: A = Wg global f16 [o][tap*64+c], B from Ot LDS [p][c].
__device__ __forceinline__ void proj_mm(const u16* __restrict__ Wg,
                                        const u16* __restrict__ Ot,
                                        int wv, int L, int q, v4f C[4])
{
#pragma unroll
    for (int nt = 0; nt < 4; ++nt) C[nt] = (v4f){0.f, 0.f, 0.f, 0.f};
    const u16* arow = Wg + (16 * wv + L) * 576;
    const int pc = L & 7;
    const int prb = L >> 3;
#pragma unroll
    for (int tap = 0; tap < 9; ++tap) {
        const int dy = tap / 3 - 1, dx = tap % 3 - 1;
        const int spc = pc + dx;
        const bool vc = (unsigned)spc < 8u;
#pragma unroll
        for (int half = 0; half < 2; ++half) {
            v8h a = *(const v8h*)(arow + tap * 64 + half * 32 + q * 8);
#pragma unroll
            for (int nt = 0; nt < 4; ++nt) {
                const int spr = nt * 2 + prb + dy;
                v8h b = (v8h)0;
                if (vc && (unsigned)spr < 8u)
                    b = *(const v8h*)(Ot + (spr * 8 + spc) * XS + half * 32 + q * 8);
                C[nt] = MFMA_F16(a, b, C[nt]);
            }
        }
    }
}

// softmax over rows in S[4] C-frags, write A f16 to Am (wave-local rows).
__device__ __forceinline__ void softmax_to_lds(v4f S[4], float invt,
                                               u16* __restrict__ Am,
                                               int rowb, int L)
{
#pragma unroll
    for (int nt = 0; nt < 4; ++nt) S[nt] *= invt;
#pragma unroll
    for (int r = 0; r < 4; ++r) {
        float mx = fmaxf(fmaxf(S[0][r], S[1][r]), fmaxf(S[2][r], S[3][r]));
        mx = fmaxf(mx, __shfl_xor(mx, 1));
        mx = fmaxf(mx, __shfl_xor(mx, 2));
        mx = fmaxf(mx, __shfl_xor(mx, 4));
        mx = fmaxf(mx, __shfl_xor(mx, 8));
        float e0 = __expf(S[0][r] - mx);
        float e1 = __expf(S[1][r] - mx);
        float e2 = __expf(S[2][r] - mx);
        float e3 = __expf(S[3][r] - mx);
        float sm = e0 + e1 + e2 + e3;
        sm += __shfl_xor(sm, 1);
        sm += __shfl_xor(sm, 2);
        sm += __shfl_xor(sm, 4);
        sm += __shfl_xor(sm, 8);
        const float ri = 1.0f / sm;
        Am[(rowb + r) * XS + L +  0] = f16r(e0 * ri);
        Am[(rowb + r) * XS + L + 16] = f16r(e1 * ri);
        Am[(rowb + r) * XS + L + 32] = f16r(e2 * ri);
        Am[(rowb + r) * XS + L + 48] = f16r(e3 * ri);
    }
}

// ---------------------------------------------------------------------------
// Weight prep: fp32 -> f16; proj weights permuted [o][c][tap] -> [o][tap*64+c].
// ---------------------------------------------------------------------------
__global__ void prep(const float* __restrict__ qk_w, const float* __restrict__ v_w,
                     const float* __restrict__ qkv_w, const float* __restrict__ pw0,
                     const float* __restrict__ pw1, u16* __restrict__ Wb)
{
    int i = blockIdx.x * 256 + threadIdx.x;   // 0..98303
    float v;
    if (i < 8192) v = qk_w[i];
    else if (i < 12288) v = v_w[i - 8192];
    else if (i < 24576) v = qkv_w[i - 12288];
    else {
        int j = i - 24576;
        const float* s = pw0;
        if (j >= 36864) { s = pw1; j -= 36864; }
        const int o = j / 576, kk = j % 576;
        const int tap = kk >> 6, c = kk & 63;
        v = s[o * 576 + c * 9 + tap];
    }
    Wb[i] = f16r(v);
}

// ---------------------------------------------------------------------------
// Branch 1. LDS: 4 x 9216 B = 36.9 KB, 7 barriers (round-6 verified, 100 us).
// k1 keeps 4 buffers: its V path (separate X input) needs an 8th barrier in
// any 3-buffer plan (round-5: +25 us) — not worth the LDS cut.
// ---------------------------------------------------------------------------
__global__ __launch_bounds__(256, 4) void k1(
    const float* __restrict__ x, const float* __restrict__ xf,
    const float* __restrict__ temp_p,
    const float* __restrict__ qk_dw, const float* __restrict__ v_dw,
    const u16* __restrict__ Wqk, const u16* __restrict__ Wv,
    const u16* __restrict__ Wp0,
    u16* __restrict__ midb)
{
    __shared__ u16 B0[64 * XS], B1[64 * XS], B2[64 * XS], B3[64 * XS];
    const int t = threadIdx.x, n = blockIdx.x;
    const int lane = t & 63, wv = t >> 6, L = lane & 15, q = lane >> 4;
    const int rowb = 16 * wv + 4 * q;
    const size_t base = (size_t)n << 12;
    const float invt = 1.0f / temp_p[0];
    const int yp = t >> 4, xx0 = (t & 15) << 4;
    const int c2b = (yp >> 3) << 5, ir = (yp & 7) << 3;
    const int dc = t >> 2, dr0 = (t & 3) << 1;

    float4 rx[4];
    {   // Xf -> B0 f16 [p][c]; issue X loads into rx
        const float* sf = xf + base + yp * 256 + xx0;
        const float* sx = x  + base + yp * 256 + xx0;
#pragma unroll
        for (int k = 0; k < 4; ++k) {
            float4 a = *(const float4*)(sf + 4 * k);
            rx[k] = *(const float4*)(sx + 4 * k);
            const int xx = xx0 + 4 * k;
            const int c = c2b + (xx >> 3), pb = ir + (xx & 7);
            B0[(pb + 0) * XS + c] = f16r(a.x);
            B0[(pb + 1) * XS + c] = f16r(a.y);
            B0[(pb + 2) * XS + c] = f16r(a.z);
            B0[(pb + 3) * XS + c] = f16r(a.w);
        }
    }
    __syncthreads();                                    // 1
    mm_stage(Wqk,        B0, B1, wv, L, q);             // Qt (fp16)
    mm_stage(Wqk + 4096, B0, B2, wv, L, q);             // Kt (fp16)
    __syncthreads();                                    // 2
    {   // X -> B3 f16
#pragma unroll
        for (int k = 0; k < 4; ++k) {
            const int xx = xx0 + 4 * k;
            const int c = c2b + (xx >> 3), pb = ir + (xx & 7);
            B3[(pb + 0) * XS + c] = f16r(rx[k].x);
            B3[(pb + 1) * XS + c] = f16r(rx[k].y);
            B3[(pb + 2) * XS + c] = f16r(rx[k].z);
            B3[(pb + 3) * XS + c] = f16r(rx[k].w);
        }
    }
    v8s rawA[4];
    dw_read(B1, dc, dr0, rawA);                         // Qt
    __syncthreads();                                    // 3
    mm_stage(Wv, B3, B0, wv, L, q);                     // Vt (fp16) -> B0
    dw_write<false, true>(qk_dw, rawA, dc, dr0, B1);    // Qhat -> B1
    v8s rawB[4];
    dw_read(B2, dc, dr0, rawB);                         // Kt
    __syncthreads();                                    // 4
    dw_write<false, true>(qk_dw + 576, rawB, dc, dr0, B2);  // Khat -> B2
    dw_read(B0, dc, dr0, rawA);                         // Vt
    dw_write<true, false>(v_dw, rawA, dc, dr0, B3);     // V^T -> B3
    __syncthreads();                                    // 5
    v4f S[4];
    mm_lds(B1, B2, wv, L, q, S);                        // S = Qhat @ Khat^T
    softmax_to_lds(S, invt, B1, rowb, L);               // A -> B1 (own rows)
    __syncthreads();                                    // 6
    v4f O[4];
    mm_lds(B1, B3, wv, L, q, O);                        // O = A @ V
#pragma unroll
    for (int nt = 0; nt < 4; ++nt)
#pragma unroll
        for (int r = 0; r < 4; ++r)
            B2[(L + 16 * nt) * XS + rowb + r] = f16r(O[nt][r]);  // O^T -> B2
    __syncthreads();                                    // 7
    v4f C[4];
    proj_mm(Wp0, B2, wv, L, q, C);
#pragma unroll
    for (int nt = 0; nt < 4; ++nt)
#pragma unroll
        for (int r = 0; r < 4; ++r) {
            const int o = rowb + r, p = L + 16 * nt;
            const int yy = ((o >> 5) << 3) + (p >> 3);
            const int xp = ((o & 31) << 3) + (p & 7);
            midb[base + yy * 256 + xp] = f16r(C[nt][r]);
        }
}

// ---------------------------------------------------------------------------
// Branch 2: reads mid (f16) with roll(-4,-4); writes fp32 out with roll(+4,+4).
// 3-buffer / 7-barrier schedule (round-5 verified, ~-23us): LDS 27648 B ->
// 5 blocks/CU. B0: in -> Vt -> V^T ; B1: Qt -> Qhat -> A ; B2: Kt -> Khat -> O^T.
// ---------------------------------------------------------------------------
__global__ __launch_bounds__(256, 4) void k2(
    const u16* __restrict__ midb, const float* __restrict__ temp_p,
    const float* __restrict__ qkv_dw,
    const u16* __restrict__ Wqkv, const u16* __restrict__ Wp1,
    float* __restrict__ out)
{
    __shared__ u16 B0[64 * XS], B1[64 * XS], B2[64 * XS];
    const int t = threadIdx.x, m = blockIdx.x;
    const int lane = t & 63, wv = t >> 6, L = lane & 15, q = lane >> 4;
    const int rowb = 16 * wv + 4 * q;
    const int plane = m >> 4, mh2 = m & 15;
    const u16* img = midb + ((size_t)plane << 16);
    const float invt = 1.0f / temp_p[0];
    const int yp = t >> 4, xx0 = (t & 15) << 4;
    const int c2b = (yp >> 3) << 5, ir = (yp & 7) << 3;
    const int dc = t >> 2, dr0 = (t & 3) << 1;

    {   // shifted strip -> B0 (pure f16 copy, no conversion)
        const int row = (mh2 * 16 + 4 + yp) & 255;
#pragma unroll
        for (int k = 0; k < 4; ++k) {
            const int cc = (xx0 + 4 + 4 * k) & 255;
            ushort4 a = *(const ushort4*)(img + row * 256 + cc);
            const int xx = xx0 + 4 * k;
            const int c = c2b + (xx >> 3), pb = ir + (xx & 7);
            B0[(pb + 0) * XS + c] = a.x;
            B0[(pb + 1) * XS + c] = a.y;
            B0[(pb + 2) * XS + c] = a.z;
            B0[(pb + 3) * XS + c] = a.w;
        }
    }
    __syncthreads();                                    // 1
    mm_stage(Wqkv,        B0, B1, wv, L, q);            // Qt
    mm_stage(Wqkv + 4096, B0, B2, wv, L, q);            // Kt
    v4f VF[4];
    mm_frags(Wqkv + 8192, B0, wv, L, q, VF);            // Vt frags (reads B0)
    __syncthreads();                                    // 2  (B0 reads done)
    mm_store(VF, B0, wv, L, q);                         // Vt fp16 -> B0 (in-place)
    v8s rawQ[4];
    dw_read(B1, dc, dr0, rawQ);
    __syncthreads();                                    // 3  (Vt ready; B1 reads done)
    dw_write<false, true>(qkv_dw, rawQ, dc, dr0, B1);   // Qhat -> B1
    v8s rawK[4];
    dw_read(B2, dc, dr0, rawK);
    v8s rawV[4];
    dw_read(B0, dc, dr0, rawV);                         // Vt
    __syncthreads();                                    // 4  (B0/B2 reads done)
    dw_write<false, true>(qkv_dw + 576, rawK, dc, dr0, B2);   // Khat -> B2
    dw_write<true, false>(qkv_dw + 1152, rawV, dc, dr0, B0);  // V^T -> B0
    __syncthreads();                                    // 5  (Qhat/Khat/V^T ready)
    v4f S[4];
    mm_lds(B1, B2, wv, L, q, S);
    softmax_to_lds(S, invt, B1, rowb, L);               // A -> B1 (own rows only)
    v4f O[4];
    mm_lds(B1, B0, wv, L, q, O);                        // O = A @ V
    __syncthreads();                                    // 6  (B2 S-reads done)
#pragma unroll
    for (int nt = 0; nt < 4; ++nt)
#pragma unroll
        for (int r = 0; r < 4; ++r)
            B2[(L + 16 * nt) * XS + rowb + r] = f16r(O[nt][r]);  // O^T -> B2
    __syncthreads();                                    // 7
    v4f C[4];
    proj_mm(Wp1, B2, wv, L, q, C);
    float* op = out + ((size_t)plane << 16);
#pragma unroll
    for (int nt = 0; nt < 4; ++nt)
#pragma unroll
        for (int r = 0; r < 4; ++r) {
            const int o = rowb + r, p = L + 16 * nt;
            const int R = mh2 * 16 + ((o >> 5) << 3) + (p >> 3);
            const int orow = (R + 4) & 255;
            const int ocol = ((o & 31) * 8 + (p & 7) + 4) & 255;
            op[orow * 256 + ocol] = C[nt][r];
        }
}

extern "C" void kernel_launch(void* const* d_in, const int* in_sizes, int n_in,
                              void* d_out, int out_size, void* d_ws, size_t ws_size,
                              hipStream_t stream)
{
    const float* x       = (const float*)d_in[0];
    const float* xf      = (const float*)d_in[1];
    const float* temp    = (const float*)d_in[2];
    const float* qk_w    = (const float*)d_in[3];
    const float* qk_dw   = (const float*)d_in[4];
    const float* v_w     = (const float*)d_in[5];
    const float* v_dw    = (const float*)d_in[6];
    const float* proj_w  = (const float*)d_in[7];
    const float* proj1_w = (const float*)d_in[8];
    const float* qkv1_w  = (const float*)d_in[9];
    const float* qkv1_dw = (const float*)d_in[10];
    float* out = (float*)d_out;

    u16* midb = (u16*)d_ws;                               // 33554432 B
    u16* Wb   = (u16*)((char*)d_ws + 33554432);           // 196608 B

    prep<<<384, 256, 0, stream>>>(qk_w, v_w, qkv1_w, proj_w, proj1_w, Wb);
    k1<<<4096, 256, 0, stream>>>(x, xf, temp, qk_dw, v_dw,
                                 Wb, Wb + 8192, Wb + 24576, midb);
    k2<<<4096, 256, 0, stream>>>(midb, temp, qkv1_dw,
                                 Wb + 12288, Wb + 61440, out);
}

// Round 8
// 291.116 us; speedup vs baseline: 1.0025x; 1.0025x over previous
//
#include <hip/hip_runtime.h>

typedef short v8s __attribute__((ext_vector_type(8)));
typedef _Float16 v8h __attribute__((ext_vector_type(8)));
typedef float v4f __attribute__((ext_vector_type(4)));
typedef unsigned short u16;

// All on-chip/intermediate tensors are fp16: values bounded (L2-normed Q/K,
// |S|<=1/temp, A<=1, conv outputs O(1)), so fp16 beats bf16 accuracy AND
// f32->f16 is 1 VALU op. MFMA f16 rate == bf16 rate on gfx950.
#define MFMA_F16(a, b, c) __builtin_amdgcn_mfma_f32_16x16x32_f16((a), (b), (c), 0, 0, 0)
#define XS 72   // row stride in 16-bit elems (144 B, 16B-aligned rows)

__device__ __forceinline__ u16 f16r(float x) {
    _Float16 h = (_Float16)x; u16 u; __builtin_memcpy(&u, &h, 2); return u;
}
__device__ __forceinline__ float f16f(u16 u) {
    _Float16 h; __builtin_memcpy(&h, &u, 2); return (float)h;
}

// ---------------------------------------------------------------------------
// Stage-1 1x1 conv pieces. mm_frags/mm_store split lets the V path run
// in-place (read buffer -> barrier -> write same buffer).
// ---------------------------------------------------------------------------
__device__ __forceinline__ void mm_frags(const u16* __restrict__ Ag,
                                         const u16* __restrict__ XB,
                                         int wv, int L, int q, v4f C[4])
{
#pragma unroll
    for (int nt = 0; nt < 4; ++nt) C[nt] = (v4f){0.f, 0.f, 0.f, 0.f};
#pragma unroll
    for (int kt = 0; kt < 2; ++kt) {
        v8h a = *(const v8h*)(Ag + (16 * wv + L) * 64 + kt * 32 + q * 8);
#pragma unroll
        for (int nt = 0; nt < 4; ++nt) {
            v8h b = *(const v8h*)(XB + (nt * 16 + L) * XS + kt * 32 + q * 8);
            C[nt] = MFMA_F16(a, b, C[nt]);
        }
    }
}
__device__ __forceinline__ void mm_store(const v4f C[4], u16* __restrict__ M,
                                         int wv, int L, int q)
{
    const int rowb = 16 * wv + 4 * q;
#pragma unroll
    for (int r = 0; r < 4; ++r)
#pragma unroll
        for (int nt = 0; nt < 4; ++nt)
            M[(rowb + r) * XS + nt * 16 + L] = f16r(C[nt][r]);
}
__device__ __forceinline__ void mm_stage(const u16* __restrict__ Ag,
                                         const u16* __restrict__ XB,
                                         u16* __restrict__ M,
                                         int wv, int L, int q)
{
    v4f C[4];
    mm_frags(Ag, XB, wv, L, q, C);
    mm_store(C, M, wv, L, q);
}

// dw 3x3 input read: channel c, spatial rows r0-1..r0+2 from fp16 [c][p].
__device__ __forceinline__ void dw_read(const u16* __restrict__ M, int c, int r0,
                                        v8s raw[4])
{
#pragma unroll
    for (int r = 0; r < 4; ++r) {
        const int rr = r0 - 1 + r;
        raw[r] = ((unsigned)rr < 8u) ? *(const v8s*)(M + c * XS + rr * 8)
                                     : (v8s){0, 0, 0, 0, 0, 0, 0, 0};
    }
}

// dw 3x3 compute + optional L2-norm + f16 write.
// TR=false: [c][p] row-major (v8s packed). TR=true: transposed [p][c] scalar.
template <bool TR, bool NORM>
__device__ __forceinline__ void dw_write(const float* __restrict__ dwg,
                                         const v8s raw[4], int c, int r0,
                                         u16* __restrict__ Out)
{
    float w[9];
#pragma unroll
    for (int k = 0; k < 9; ++k) w[k] = dwg[c * 9 + k];
    float in[4][10];
#pragma unroll
    for (int r = 0; r < 4; ++r) {
        in[r][0] = 0.f; in[r][9] = 0.f;
#pragma unroll
        for (int j = 0; j < 8; ++j) in[r][j + 1] = f16f((u16)raw[r][j]);
    }
    float o[2][8];
#pragma unroll
    for (int rr = 0; rr < 2; ++rr)
#pragma unroll
        for (int j = 0; j < 8; ++j) {
            float s;
            s = w[0] * in[rr][j];
            s = fmaf(w[1], in[rr][j + 1], s);
            s = fmaf(w[2], in[rr][j + 2], s);
            s = fmaf(w[3], in[rr + 1][j], s);
            s = fmaf(w[4], in[rr + 1][j + 1], s);
            s = fmaf(w[5], in[rr + 1][j + 2], s);
            s = fmaf(w[6], in[rr + 2][j], s);
            s = fmaf(w[7], in[rr + 2][j + 1], s);
            s = fmaf(w[8], in[rr + 2][j + 2], s);
            o[rr][j] = s;
        }
    if (NORM) {
        float ss = 0.f;
#pragma unroll
        for (int rr = 0; rr < 2; ++rr)
#pragma unroll
            for (int j = 0; j < 8; ++j) ss = fmaf(o[rr][j], o[rr][j], ss);
        ss += __shfl_xor(ss, 1);
        ss += __shfl_xor(ss, 2);
        const float sc = 1.0f / fmaxf(sqrtf(ss), 1e-12f);
#pragma unroll
        for (int rr = 0; rr < 2; ++rr)
#pragma unroll
            for (int j = 0; j < 8; ++j) o[rr][j] *= sc;
    }
    if (TR) {
#pragma unroll
        for (int rr = 0; rr < 2; ++rr)
#pragma unroll
            for (int j = 0; j < 8; ++j)
                Out[((r0 + rr) * 8 + j) * XS + c] = f16r(o[rr][j]);
    } else {
#pragma unroll
        for (int rr = 0; rr < 2; ++rr) {
            v8s v;
#pragma unroll
            for (int j = 0; j < 8; ++j) v[j] = (short)f16r(o[rr][j]);
            *(v8s*)(Out + c * XS + (r0 + rr) * 8) = v;
        }
    }
}

// 64x64x64 D[m][n] = sum_k A[m][k]*B[n][k], both f16 LDS, wave stripe rows.
__device__ __forceinline__ void mm_lds(const u16* __restrict__ Am,
                                       const u16* __restrict__ Bm,
                                       int wv, int L, int q, v4f C[4])
{
#pragma unroll
    for (int nt = 0; nt < 4; ++nt) C[nt] = (v4f){0.f, 0.f, 0.f, 0.f};
#pragma unroll
    for (int kt = 0; kt < 2; ++kt) {
        v8h a = *(const v8h*)(Am + (16 * wv + L) * XS + kt * 32 + q * 8);
#pragma unroll
        for (int nt = 0; nt < 4; ++nt) {
            v8h b = *(const v8h*)(Bm + (nt * 16 + L) * XS + kt * 32 + q * 8);
            C[nt] = MFMA_F16(a, b, C[nt]);
        }
    }
}

// proj 3x3 dense: A = Wg global f16 [o][tap*64+c], B from Ot LDS [p][c].
__device__ __forceinline__ void proj_mm(const u16* __restrict__ Wg,
                                        const u16* __restrict__ Ot,
                                        int wv, int L, int q, v4f C[4])
{
#pragma unroll
    for (int nt = 0; nt < 4; ++nt) C[nt] = (v4f){0.f, 0.f, 0.f, 0.f};
    const u16* arow = Wg + (16 * wv + L) * 576;
    const int pc = L & 7;
    const int prb = L >> 3;
#pragma unroll
    for (int tap = 0; tap < 9; ++tap) {
        const int dy = tap / 3 - 1, dx = tap % 3 - 1;
        const int spc = pc + dx;
        const bool vc = (unsigned)spc < 8u;
#pragma unroll
        for (int half = 0; half < 2; ++half) {
            v8h a = *(const v8h*)(arow + tap * 64 + half * 32 + q * 8);
#pragma unroll
            for (int nt = 0; nt < 4; ++nt) {
                const int spr = nt * 2 + prb + dy;
                v8h b = (v8h)0;
                if (vc && (unsigned)spr < 8u)
                    b = *(const v8h*)(Ot + (spr * 8 + spc) * XS + half * 32 + q * 8);
                C[nt] = MFMA_F16(a, b, C[nt]);
            }
        }
    }
}

// softmax over rows in S[4] C-frags, write A f16 to Am (wave-local rows).
__device__ __forceinline__ void softmax_to_lds(v4f S[4], float invt,
                                               u16* __restrict__ Am,
                                               int rowb, int L)
{
#pragma unroll
    for (int nt = 0; nt < 4; ++nt) S[nt] *= invt;
#pragma unroll
    for (int r = 0; r < 4; ++r) {
        float mx = fmaxf(fmaxf(S[0][r], S[1][r]), fmaxf(S[2][r], S[3][r]));
        mx = fmaxf(mx, __shfl_xor(mx, 1));
        mx = fmaxf(mx, __shfl_xor(mx, 2));
        mx = fmaxf(mx, __shfl_xor(mx, 4));
        mx = fmaxf(mx, __shfl_xor(mx, 8));
        float e0 = __expf(S[0][r] - mx);
        float e1 = __expf(S[1][r] - mx);
        float e2 = __expf(S[2][r] - mx);
        float e3 = __expf(S[3][r] - mx);
        float sm = e0 + e1 + e2 + e3;
        sm += __shfl_xor(sm, 1);
        sm += __shfl_xor(sm, 2);
        sm += __shfl_xor(sm, 4);
        sm += __shfl_xor(sm, 8);
        const float ri = 1.0f / sm;
        Am[(rowb + r) * XS + L +  0] = f16r(e0 * ri);
        Am[(rowb + r) * XS + L + 16] = f16r(e1 * ri);
        Am[(rowb + r) * XS + L + 32] = f16r(e2 * ri);
        Am[(rowb + r) * XS + L + 48] = f16r(e3 * ri);
    }
}

// ---------------------------------------------------------------------------
// Weight prep: fp32 -> f16; proj weights permuted [o][c][tap] -> [o][tap*64+c].
// ---------------------------------------------------------------------------
__global__ void prep(const float* __restrict__ qk_w, const float* __restrict__ v_w,
                     const float* __restrict__ qkv_w, const float* __restrict__ pw0,
                     const float* __restrict__ pw1, u16* __restrict__ Wb)
{
    int i = blockIdx.x * 256 + threadIdx.x;   // 0..98303
    float v;
    if (i < 8192) v = qk_w[i];
    else if (i < 12288) v = v_w[i - 8192];
    else if (i < 24576) v = qkv_w[i - 12288];
    else {
        int j = i - 24576;
        const float* s = pw0;
        if (j >= 36864) { s = pw1; j -= 36864; }
        const int o = j / 576, kk = j % 576;
        const int tap = kk >> 6, c = kk & 63;
        v = s[o * 576 + c * 9 + tap];
    }
    Wb[i] = f16r(v);
}

// ---------------------------------------------------------------------------
// Branch 1, rescheduled to k2's proven phase shape:
//  P1 stage Xf->B0, X->B3 | P2 [prio] Qt,Kt,VF (24 MFMA clustered)
//  P3 VF->B3 in-place + dwread Q | P4 dwQhat + dwread K,V | P5 dwKhat + V^T->B0
//  P6 [prio] S -> softmax -> O (no barrier inside: O's a-frags are wave-own A
//  rows, b-frags are V^T written P5) | P7 O^T->B2 | P8 [prio] proj -> midb.
// 7 barriers; removes old dead staging phase + softmax->O barrier.
// ---------------------------------------------------------------------------
__global__ __launch_bounds__(256, 4) void k1(
    const float* __restrict__ x, const float* __restrict__ xf,
    const float* __restrict__ temp_p,
    const float* __restrict__ qk_dw, const float* __restrict__ v_dw,
    const u16* __restrict__ Wqk, const u16* __restrict__ Wv,
    const u16* __restrict__ Wp0,
    u16* __restrict__ midb)
{
    __shared__ u16 B0[64 * XS], B1[64 * XS], B2[64 * XS], B3[64 * XS];
    const int t = threadIdx.x, n = blockIdx.x;
    const int lane = t & 63, wv = t >> 6, L = lane & 15, q = lane >> 4;
    const int rowb = 16 * wv + 4 * q;
    const size_t base = (size_t)n << 12;
    const float invt = 1.0f / temp_p[0];
    const int yp = t >> 4, xx0 = (t & 15) << 4;
    const int c2b = (yp >> 3) << 5, ir = (yp & 7) << 3;
    const int dc = t >> 2, dr0 = (t & 3) << 1;

    {   // P1: Xf -> B0, X -> B3 (both staged up front)
        const float* sf = xf + base + yp * 256 + xx0;
        const float* sx = x  + base + yp * 256 + xx0;
#pragma unroll
        for (int k = 0; k < 4; ++k) {
            float4 a = *(const float4*)(sf + 4 * k);
            float4 b = *(const float4*)(sx + 4 * k);
            const int xx = xx0 + 4 * k;
            const int c = c2b + (xx >> 3), pb = ir + (xx & 7);
            B0[(pb + 0) * XS + c] = f16r(a.x);
            B0[(pb + 1) * XS + c] = f16r(a.y);
            B0[(pb + 2) * XS + c] = f16r(a.z);
            B0[(pb + 3) * XS + c] = f16r(a.w);
            B3[(pb + 0) * XS + c] = f16r(b.x);
            B3[(pb + 1) * XS + c] = f16r(b.y);
            B3[(pb + 2) * XS + c] = f16r(b.z);
            B3[(pb + 3) * XS + c] = f16r(b.w);
        }
    }
    __syncthreads();                                    // 1
    __builtin_amdgcn_s_setprio(1);
    mm_stage(Wqk,        B0, B1, wv, L, q);             // Qt (fp16) -> B1
    mm_stage(Wqk + 4096, B0, B2, wv, L, q);             // Kt (fp16) -> B2
    v4f VF[4];
    mm_frags(Wv, B3, wv, L, q, VF);                     // Vt frags (reads B3=X)
    __builtin_amdgcn_s_setprio(0);
    __syncthreads();                                    // 2  (B0/B3 reads done)
    mm_store(VF, B3, wv, L, q);                         // Vt fp16 -> B3 in-place
    v8s rawQ[4];
    dw_read(B1, dc, dr0, rawQ);                         // Qt
    __syncthreads();                                    // 3  (Vt ready; B1 reads done)
    dw_write<false, true>(qk_dw, rawQ, dc, dr0, B1);    // Qhat -> B1
    v8s rawK[4];
    dw_read(B2, dc, dr0, rawK);                         // Kt
    v8s rawV[4];
    dw_read(B3, dc, dr0, rawV);                         // Vt
    __syncthreads();                                    // 4  (B2/B3 reads done)
    dw_write<false, true>(qk_dw + 576, rawK, dc, dr0, B2);  // Khat -> B2
    dw_write<true, false>(v_dw, rawV, dc, dr0, B0);     // V^T -> B0 (Xf dead)
    __syncthreads();                                    // 5  (Qhat/Khat/V^T ready)
    v4f S[4];
    __builtin_amdgcn_s_setprio(1);
    mm_lds(B1, B2, wv, L, q, S);                        // S = Qhat @ Khat^T
    __builtin_amdgcn_s_setprio(0);
    softmax_to_lds(S, invt, B1, rowb, L);               // A -> B1 (own rows)
    v4f O[4];
    __builtin_amdgcn_s_setprio(1);
    mm_lds(B1, B0, wv, L, q, O);                        // O = A @ V (a=own rows)
    __builtin_amdgcn_s_setprio(0);
    __syncthreads();                                    // 6  (B2 S-reads done)
#pragma unroll
    for (int nt = 0; nt < 4; ++nt)
#pragma unroll
        for (int r = 0; r < 4; ++r)
            B2[(L + 16 * nt) * XS + rowb + r] = f16r(O[nt][r]);  // O^T -> B2
    __syncthreads();                                    // 7
    v4f C[4];
    __builtin_amdgcn_s_setprio(1);
    proj_mm(Wp0, B2, wv, L, q, C);
    __builtin_amdgcn_s_setprio(0);
#pragma unroll
    for (int nt = 0; nt < 4; ++nt)
#pragma unroll
        for (int r = 0; r < 4; ++r) {
            const int o = rowb + r, p = L + 16 * nt;
            const int yy = ((o >> 5) << 3) + (p >> 3);
            const int xp = ((o & 31) << 3) + (p & 7);
            midb[base + yy * 256 + xp] = f16r(C[nt][r]);
        }
}

// ---------------------------------------------------------------------------
// Branch 2: reads mid (f16) with roll(-4,-4); writes fp32 out with roll(+4,+4).
// 3-buffer / 7-barrier schedule. B0: in -> Vt -> V^T ; B1: Qt -> Qhat -> A ;
// B2: Kt -> Khat -> O^T.
// ---------------------------------------------------------------------------
__global__ __launch_bounds__(256, 4) void k2(
    const u16* __restrict__ midb, const float* __restrict__ temp_p,
    const float* __restrict__ qkv_dw,
    const u16* __restrict__ Wqkv, const u16* __restrict__ Wp1,
    float* __restrict__ out)
{
    __shared__ u16 B0[64 * XS], B1[64 * XS], B2[64 * XS];
    const int t = threadIdx.x, m = blockIdx.x;
    const int lane = t & 63, wv = t >> 6, L = lane & 15, q = lane >> 4;
    const int rowb = 16 * wv + 4 * q;
    const int plane = m >> 4, mh2 = m & 15;
    const u16* img = midb + ((size_t)plane << 16);
    const float invt = 1.0f / temp_p[0];
    const int yp = t >> 4, xx0 = (t & 15) << 4;
    const int c2b = (yp >> 3) << 5, ir = (yp & 7) << 3;
    const int dc = t >> 2, dr0 = (t & 3) << 1;

    {   // shifted strip -> B0 (pure f16 copy, no conversion)
        const int row = (mh2 * 16 + 4 + yp) & 255;
#pragma unroll
        for (int k = 0; k < 4; ++k) {
            const int cc = (xx0 + 4 + 4 * k) & 255;
            ushort4 a = *(const ushort4*)(img + row * 256 + cc);
            const int xx = xx0 + 4 * k;
            const int c = c2b + (xx >> 3), pb = ir + (xx & 7);
            B0[(pb + 0) * XS + c] = a.x;
            B0[(pb + 1) * XS + c] = a.y;
            B0[(pb + 2) * XS + c] = a.z;
            B0[(pb + 3) * XS + c] = a.w;
        }
    }
    __syncthreads();                                    // 1
    __builtin_amdgcn_s_setprio(1);
    mm_stage(Wqkv,        B0, B1, wv, L, q);            // Qt
    mm_stage(Wqkv + 4096, B0, B2, wv, L, q);            // Kt
    v4f VF[4];
    mm_frags(Wqkv + 8192, B0, wv, L, q, VF);            // Vt frags (reads B0)
    __builtin_amdgcn_s_setprio(0);
    __syncthreads();                                    // 2  (B0 reads done)
    mm_store(VF, B0, wv, L, q);                         // Vt fp16 -> B0 (in-place)
    v8s rawQ[4];
    dw_read(B1, dc, dr0, rawQ);
    __syncthreads();                                    // 3  (Vt ready; B1 reads done)
    dw_write<false, true>(qkv_dw, rawQ, dc, dr0, B1);   // Qhat -> B1
    v8s rawK[4];
    dw_read(B2, dc, dr0, rawK);
    v8s rawV[4];
    dw_read(B0, dc, dr0, rawV);                         // Vt
    __syncthreads();                                    // 4  (B0/B2 reads done)
    dw_write<false, true>(qkv_dw + 576, rawK, dc, dr0, B2);   // Khat -> B2
    dw_write<true, false>(qkv_dw + 1152, rawV, dc, dr0, B0);  // V^T -> B0
    __syncthreads();                                    // 5  (Qhat/Khat/V^T ready)
    v4f S[4];
    __builtin_amdgcn_s_setprio(1);
    mm_lds(B1, B2, wv, L, q, S);
    __builtin_amdgcn_s_setprio(0);
    softmax_to_lds(S, invt, B1, rowb, L);               // A -> B1 (own rows only)
    v4f O[4];
    __builtin_amdgcn_s_setprio(1);
    mm_lds(B1, B0, wv, L, q, O);                        // O = A @ V
    __builtin_amdgcn_s_setprio(0);
    __syncthreads();                                    // 6  (B2 S-reads done)
#pragma unroll
    for (int nt = 0; nt < 4; ++nt)
#pragma unroll
        for (int r = 0; r < 4; ++r)
            B2[(L + 16 * nt) * XS + rowb + r] = f16r(O[nt][r]);  // O^T -> B2
    __syncthreads();                                    // 7
    v4f C[4];
    __builtin_amdgcn_s_setprio(1);
    proj_mm(Wp1, B2, wv, L, q, C);
    __builtin_amdgcn_s_setprio(0);
    float* op = out + ((size_t)plane << 16);
#pragma unroll
    for (int nt = 0; nt < 4; ++nt)
#pragma unroll
        for (int r = 0; r < 4; ++r) {
            const int o = rowb + r, p = L + 16 * nt;
            const int R = mh2 * 16 + ((o >> 5) << 3) + (p >> 3);
            const int orow = (R + 4) & 255;
            const int ocol = ((o & 31) * 8 + (p & 7) + 4) & 255;
            op[orow * 256 + ocol] = C[nt][r];
        }
}

extern "C" void kernel_launch(void* const* d_in, const int* in_sizes, int n_in,
                              void* d_out, int out_size, void* d_ws, size_t ws_size,
                              hipStream_t stream)
{
    const float* x       = (const float*)d_in[0];
    const float* xf      = (const float*)d_in[1];
    const float* temp    = (const float*)d_in[2];
    const float* qk_w    = (const float*)d_in[3];
    const float* qk_dw   = (const float*)d_in[4];
    const float* v_w     = (const float*)d_in[5];
    const float* v_dw    = (const float*)d_in[6];
    const float* proj_w  = (const float*)d_in[7];
    const float* proj1_w = (const float*)d_in[8];
    const float* qkv1_w  = (const float*)d_in[9];
    const float* qkv1_dw = (const float*)d_in[10];
    float* out = (float*)d_out;

    u16* midb = (u16*)d_ws;                               // 33554432 B
    u16* Wb   = (u16*)((char*)d_ws + 33554432);           // 196608 B

    prep<<<384, 256, 0, stream>>>(qk_w, v_w, qkv1_w, proj_w, proj1_w, Wb);
    k1<<<4096, 256, 0, stream>>>(x, xf, temp, qk_dw, v_dw,
                                 Wb, Wb + 8192, Wb + 24576, midb);
    k2<<<4096, 256, 0, stream>>>(midb, temp, qkv1_dw,
                                 Wb + 12288, Wb + 61440, out);
}